// Round 3
// baseline (754.939 us; speedup 1.0000x reference)
//
#include <hip/hip_runtime.h>
#include <hip/hip_bf16.h>

#define NPTS 8192
#define KN   32
#define DIM  256
#define DH   128
#define DOUT 512

typedef __attribute__((ext_vector_type(8))) short bf16x8;
typedef __attribute__((ext_vector_type(4))) short short4v;
typedef __attribute__((ext_vector_type(4))) float f32x4;

#define MFMA16(a, b, c) __builtin_amdgcn_mfma_f32_16x16x32_bf16((a), (b), (c), 0, 0, 0)

__device__ __forceinline__ short f2b(float f) {
    __hip_bfloat16 h = __float2bfloat16(f);
    return *reinterpret_cast<short*>(&h);
}

// ---------------- ws layout (bytes) ----------------
#define WSO_QATTN 0u                      // float[8192*256]
#define WSO_WKT   16777216u               // short[65536]  -WkT[o][i]  (negated!)
#define WSO_WVT   16908288u               // short[65536]
#define WSO_G1T   17039360u               // short[65536]
#define WSO_G2T   17170432u               // short[65536]
#define WSO_D2T   17301504u               // short[32768]  d2T[o=256][i=128]

// ================= prep 1: weights -> bf16 transposed =================
extern "C" __global__ __launch_bounds__(256)
void prep_w(const float* __restrict__ Wk, const float* __restrict__ Wv,
            const float* __restrict__ g1w, const float* __restrict__ g2w,
            const float* __restrict__ d2w,
            short* __restrict__ wkT, short* __restrict__ wvT,
            short* __restrict__ g1T, short* __restrict__ g2T,
            short* __restrict__ d2T)
{
    const int idx = blockIdx.x * 256 + threadIdx.x;
    if (idx < 65536) {
        const int o = idx >> 8, i = idx & 255;
        wkT[idx] = f2b(-Wk[i * 256 + o]);          // NEGATED: h accumulates -k_attn
        wvT[idx] = f2b(Wv[i * 256 + o]);
        g1T[idx] = f2b(g1w[i * 256 + o]);
        g2T[idx] = f2b(g2w[i * 256 + o]);
    }
    if (idx < 32768) {
        const int o = idx >> 7, i = idx & 127;
        d2T[idx] = f2b(d2w[i * 256 + o]);
    }
}

// ================= prep 2: q_attn = feats_q @ Wq (fp32), 32 rows/block ==========
extern "C" __global__ __launch_bounds__(256)
void prep_q(const float* __restrict__ feats_q, const float* __restrict__ Wq,
            const float* __restrict__ xyz_q, float* __restrict__ q_attn,
            float* __restrict__ out)
{
    const int b = blockIdx.x;
    const int t = threadIdx.x;
    if (b >= 256) {                        // 96 blocks: xyz passthrough
        const int idx = (b - 256) * 256 + t;
        out[idx] = xyz_q[idx];
        return;
    }
    __shared__ float s_q[32][256];
    for (int j = 0; j < 32; ++j)
        s_q[j][t] = feats_q[(size_t)(b * 32 + j) * 256 + t];
    __syncthreads();
    float acc[32];
    #pragma unroll
    for (int pt = 0; pt < 32; ++pt) acc[pt] = 0.f;
    for (int k = 0; k < 256; k += 4) {
        float wv0 = Wq[(k + 0) * 256 + t];
        float wv1 = Wq[(k + 1) * 256 + t];
        float wv2 = Wq[(k + 2) * 256 + t];
        float wv3 = Wq[(k + 3) * 256 + t];
        #pragma unroll
        for (int pt = 0; pt < 32; ++pt) {
            const float4 sv = *(const float4*)&s_q[pt][k];
            acc[pt] = fmaf(sv.x, wv0, acc[pt]);
            acc[pt] = fmaf(sv.y, wv1, acc[pt]);
            acc[pt] = fmaf(sv.z, wv2, acc[pt]);
            acc[pt] = fmaf(sv.w, wv3, acc[pt]);
        }
    }
    #pragma unroll
    for (int pt = 0; pt < 32; ++pt)
        q_attn[(size_t)(b * 32 + pt) * 256 + t] = acc[pt];
}

// ====== main: 4 points/block, 16 waves (1024 thr), M=128, 16 cols per wave ======
// LDS (dynamic 64KB shorts): F  [0,16384)     feats half, 128 rows x 128 k
//                            R1 [16384,32768)  r1, 128 rows x 128 k
//                            H  [0,32768)      h/t, 128 rows x 256 (overlays F,R1)
//                            s_res = float[4][256] at base (overlays dead H at end)
// tiles XOR-swizzled: elem = row*LD + (c ^ ((row&7)<<3))

#define STAGE_FEATS(koff)                                                         \
    {                                                                             \
        const float* fp_ = feats_kv + ((size_t)p0 * KN + srow) * DIM + (koff) +   \
                           sc * 16;                                               \
        _Pragma("unroll")                                                         \
        for (int j_ = 0; j_ < 4; ++j_) {                                          \
            const float4 v_ = *(const float4*)(fp_ + 4 * j_);                     \
            const int c2_ = sc * 16 + 4 * j_;                                     \
            short4v t_;                                                           \
            t_[0] = f2b(v_.x); t_[1] = f2b(v_.y);                                 \
            t_[2] = f2b(v_.z); t_[3] = f2b(v_.w);                                 \
            *(short4v*)&s_lds[srow * 128 + (c2_ ^ ((srow & 7) << 3))] = t_;       \
        }                                                                         \
    }

extern "C" __global__ __launch_bounds__(1024, 4)
void ctb_main(const float* __restrict__ xyz_q, const float* __restrict__ xyz_kv,
              const float* __restrict__ feats_kv,
              const float* __restrict__ d1w, const float* __restrict__ d1b,
              const float* __restrict__ d2b, const float* __restrict__ g1b,
              const float* __restrict__ g2b,
              const float* __restrict__ q_attn,
              const short* __restrict__ wkTn, const short* __restrict__ wvT,
              const short* __restrict__ g1T, const short* __restrict__ g2T,
              const short* __restrict__ d2T,
              const float* __restrict__ ow, const float* __restrict__ ob,
              float* __restrict__ out)
{
    extern __shared__ short s_lds[];
    const int t    = threadIdx.x;
    const int w    = t >> 6;       // 0..15
    const int lane = t & 63;
    const int q    = lane >> 4;
    const int ln   = lane & 15;
    const int p0   = blockIdx.x * 4;
    const int colb = 16 * w + ln;  // this wave's column (one 16-col slice)

    const int srow = t >> 3;       // 0..127 staging row
    const int sc   = t & 7;        // 0..7   staging chunk (16 shorts)

    // ---------- stage feats half-0 (k 0..127) + r1 (cooperative) ----------
    STAGE_FEATS(0);
    {
        const int pt = srow >> 5;
        const float qx = xyz_q[(p0 + pt) * 3 + 0];
        const float qy = xyz_q[(p0 + pt) * 3 + 1];
        const float qz = xyz_q[(p0 + pt) * 3 + 2];
        const float* xk = xyz_kv + ((size_t)p0 * KN + srow) * 3;
        const float rx = qx - xk[0], ry = qy - xk[1], rz = qz - xk[2];
        #pragma unroll
        for (int j = 0; j < 16; ++j) {
            const int c = sc * 16 + j;
            const float v = fmaxf(fmaf(rx, d1w[c],
                                  fmaf(ry, d1w[DH + c],
                                  fmaf(rz, d1w[2 * DH + c], d1b[c]))), 0.f);
            s_lds[16384 + srow * 128 + (c ^ ((srow & 7) << 3))] = f2b(v);
        }
    }
    __syncthreads();

    // ---------- phase 1: vp = d2b + pos + v ; h = pos + q - k -> H ----------
    f32x4 vp[8];
    {
        const float bb0 = d2b[colb];
        #pragma unroll
        for (int mt = 0; mt < 8; ++mt) vp[mt] = (f32x4){bb0, bb0, bb0, bb0};
    }
    #pragma unroll
    for (int ks = 0; ks < 4; ++ks) {                 // pos: K=128, A from R1
        bf16x8 ar[8];
        #pragma unroll
        for (int mt = 0; mt < 8; ++mt) {
            const int row = 16 * mt + ln;
            ar[mt] = *(const bf16x8*)&s_lds[16384 + row * 128 +
                                            ((32 * ks + 8 * q) ^ ((row & 7) << 3))];
        }
        const bf16x8 bb = *(const bf16x8*)(d2T + colb * DH + 32 * ks + 8 * q);
        #pragma unroll
        for (int mt = 0; mt < 8; ++mt) vp[mt] = MFMA16(ar[mt], bb, vp[mt]);
    }
    f32x4 hacc[8];                                   // h starts from pos + q_attn
    {
        float qv[4];
        #pragma unroll
        for (int pt = 0; pt < 4; ++pt)
            qv[pt] = q_attn[(size_t)(p0 + pt) * DIM + colb];
        #pragma unroll
        for (int mt = 0; mt < 8; ++mt)
            #pragma unroll
            for (int r = 0; r < 4; ++r) hacc[mt][r] = vp[mt][r] + qv[mt >> 1];
    }
    for (int half = 0; half < 2; ++half) {           // kv: K=256 in 2 staged halves
        if (half) {
            __syncthreads();
            STAGE_FEATS(128);
            __syncthreads();
        }
        #pragma unroll
        for (int ksl = 0; ksl < 4; ++ksl) {
            bf16x8 af[8];
            #pragma unroll
            for (int mt = 0; mt < 8; ++mt) {
                const int row = 16 * mt + ln;
                af[mt] = *(const bf16x8*)&s_lds[row * 128 +
                                                ((32 * ksl + 8 * q) ^ ((row & 7) << 3))];
            }
            const int co = colb * DIM + 32 * (4 * half + ksl) + 8 * q;
            const bf16x8 bk = *(const bf16x8*)(wkTn + co);
            const bf16x8 bv = *(const bf16x8*)(wvT + co);
            #pragma unroll
            for (int mt = 0; mt < 8; ++mt) {
                hacc[mt] = MFMA16(af[mt], bk, hacc[mt]);
                vp[mt]   = MFMA16(af[mt], bv, vp[mt]);
            }
        }
    }
    __syncthreads();                                 // F, R1 now dead
    #pragma unroll
    for (int mt = 0; mt < 8; ++mt)                   // write h -> H (overlays F,R1)
        #pragma unroll
        for (int r = 0; r < 4; ++r) {
            const int row = 16 * mt + 4 * q + r;
            s_lds[row * 256 + (colb ^ ((row & 7) << 3))] = f2b(hacc[mt][r]);
        }
    __syncthreads();

    // ---------- phase 2: t = relu(h @ g1 + g1b) -> H (in place) ----------
    {
        f32x4 tacc[8];
        const float bb0 = g1b[colb];
        #pragma unroll
        for (int mt = 0; mt < 8; ++mt) tacc[mt] = (f32x4){bb0, bb0, bb0, bb0};
        #pragma unroll
        for (int ks = 0; ks < 8; ++ks) {
            bf16x8 ah[8];
            #pragma unroll
            for (int mt = 0; mt < 8; ++mt) {
                const int row = 16 * mt + ln;
                ah[mt] = *(const bf16x8*)&s_lds[row * 256 +
                                                ((32 * ks + 8 * q) ^ ((row & 7) << 3))];
            }
            const bf16x8 bb = *(const bf16x8*)(g1T + colb * DIM + 32 * ks + 8 * q);
            #pragma unroll
            for (int mt = 0; mt < 8; ++mt) tacc[mt] = MFMA16(ah[mt], bb, tacc[mt]);
        }
        __syncthreads();                             // all reads of h done
        #pragma unroll
        for (int mt = 0; mt < 8; ++mt)
            #pragma unroll
            for (int r = 0; r < 4; ++r) {
                const int row = 16 * mt + 4 * q + r;
                s_lds[row * 256 + (colb ^ ((row & 7) << 3))] =
                    f2b(fmaxf(tacc[mt][r], 0.f));
            }
        __syncthreads();
    }

    // ---------- phase 3: ap = t@g2+g2b -> softmax_k -> res = sum ap*vp ----------
    float rres[4];
    {
        f32x4 ap[8];
        const float bb0 = g2b[colb];
        #pragma unroll
        for (int mt = 0; mt < 8; ++mt) ap[mt] = (f32x4){bb0, bb0, bb0, bb0};
        #pragma unroll
        for (int ks = 0; ks < 8; ++ks) {
            bf16x8 at[8];
            #pragma unroll
            for (int mt = 0; mt < 8; ++mt) {
                const int row = 16 * mt + ln;
                at[mt] = *(const bf16x8*)&s_lds[row * 256 +
                                                ((32 * ks + 8 * q) ^ ((row & 7) << 3))];
            }
            const bf16x8 bb = *(const bf16x8*)(g2T + colb * DIM + 32 * ks + 8 * q);
            #pragma unroll
            for (int mt = 0; mt < 8; ++mt) ap[mt] = MFMA16(at[mt], bb, ap[mt]);
        }

        // per-point softmax over 32 neighbors (rows 2pt,2pt+1 x quads x r)
        #pragma unroll
        for (int pt = 0; pt < 4; ++pt) {
            float m = -1e30f;
            #pragma unroll
            for (int m2 = 0; m2 < 2; ++m2)
                #pragma unroll
                for (int r = 0; r < 4; ++r) m = fmaxf(m, ap[2 * pt + m2][r]);
            m = fmaxf(m, __shfl_xor(m, 16, 64));
            m = fmaxf(m, __shfl_xor(m, 32, 64));
            float s = 0.f;
            #pragma unroll
            for (int m2 = 0; m2 < 2; ++m2)
                #pragma unroll
                for (int r = 0; r < 4; ++r) {
                    const float e = __expf(ap[2 * pt + m2][r] - m);
                    ap[2 * pt + m2][r] = e;
                    s += e;
                }
            s += __shfl_xor(s, 16, 64);
            s += __shfl_xor(s, 32, 64);
            float racc = 0.f;
            #pragma unroll
            for (int m2 = 0; m2 < 2; ++m2)
                #pragma unroll
                for (int r = 0; r < 4; ++r)
                    racc = fmaf(ap[2 * pt + m2][r], vp[2 * pt + m2][r], racc);
            racc += __shfl_xor(racc, 16, 64);
            racc += __shfl_xor(racc, 32, 64);
            rres[pt] = racc / s;
        }
    }
    __syncthreads();                                 // all H reads complete
    float* s_res = (float*)s_lds;                    // [4][256] overlays dead H
    if (q == 0) {
        #pragma unroll
        for (int pt = 0; pt < 4; ++pt) s_res[pt * 256 + colb] = rres[pt];
    }
    __syncthreads();

    // ---------- fused out: out[4][512] = res @ ow + ob (f32) ----------
    {
        const int c  = t & 511;
        const int p2 = t >> 9;                       // 0..1 -> rows {2p2, 2p2+1}
        float a0 = ob[c], a1 = ob[c];
        const float* r0 = s_res + (2 * p2) * 256;
        const float* r1 = s_res + (2 * p2 + 1) * 256;
        #pragma unroll 8
        for (int k = 0; k < 256; ++k) {
            const float wv = ow[(size_t)k * DOUT + c];
            a0 = fmaf(r0[k], wv, a0);
            a1 = fmaf(r1[k], wv, a1);
        }
        float* o = out + (size_t)NPTS * 3;
        o[(size_t)(p0 + 2 * p2) * DOUT + c]     = a0;
        o[(size_t)(p0 + 2 * p2 + 1) * DOUT + c] = a1;
    }
}

// ================= launch =================
extern "C" void kernel_launch(void* const* d_in, const int* in_sizes, int n_in,
                              void* d_out, int out_size, void* d_ws, size_t ws_size,
                              hipStream_t stream) {
    const float* xyz_q    = (const float*)d_in[0];
    const float* feats_q  = (const float*)d_in[1];
    const float* xyz_kv   = (const float*)d_in[2];
    const float* feats_kv = (const float*)d_in[3];
    const float* Wq       = (const float*)d_in[4];
    const float* Wk       = (const float*)d_in[5];
    const float* Wv       = (const float*)d_in[6];
    const float* d1w      = (const float*)d_in[7];
    const float* d1b      = (const float*)d_in[8];
    const float* d2w      = (const float*)d_in[9];
    const float* d2b      = (const float*)d_in[10];
    const float* g1w      = (const float*)d_in[11];
    const float* g1b      = (const float*)d_in[12];
    const float* g2w      = (const float*)d_in[13];
    const float* g2b      = (const float*)d_in[14];
    const float* ow       = (const float*)d_in[15];
    const float* ob       = (const float*)d_in[16];
    float* out = (float*)d_out;

    char* ws = (char*)d_ws;
    float* q_attn = (float*)(ws + WSO_QATTN);
    short* wkT    = (short*)(ws + WSO_WKT);
    short* wvT    = (short*)(ws + WSO_WVT);
    short* g1T    = (short*)(ws + WSO_G1T);
    short* g2T    = (short*)(ws + WSO_G2T);
    short* d2T    = (short*)(ws + WSO_D2T);

    prep_w<<<dim3(256), dim3(256), 0, stream>>>(Wk, Wv, g1w, g2w, d2w,
                                                wkT, wvT, g1T, g2T, d2T);
    prep_q<<<dim3(352), dim3(256), 0, stream>>>(feats_q, Wq, xyz_q, q_attn, out);
    ctb_main<<<dim3(2048), dim3(1024), 65536, stream>>>(
        xyz_q, xyz_kv, feats_kv, d1w, d1b, d2b, g1b, g2b,
        q_attn, wkT, wvT, g1T, g2T, d2T, ow, ob, out);
}